// Round 2
// baseline (6296.684 us; speedup 1.0000x reference)
//
#include <hip/hip_runtime.h>
#include <math.h>

#define B_  4
#define D_  1024
#define T_  512
#define V_  32000
#define CD_ 4096
#define NR  (B_*T_)          // 2048 rows
#define VT  (V_/128)         // 250 v-tiles

// ---------------------------------------------------------------------------
// GEMM1: proj[V][D] = codebook[V][CD] @ cb_w[D][CD]^T + cb_b[D]
// NT f32, 128x128 tile, BK=32, 256 threads, 8x8 per thread
// ---------------------------------------------------------------------------
__global__ __launch_bounds__(256) void vq_gemm1(const float* __restrict__ A,
                                                const float* __restrict__ Bm,
                                                const float* __restrict__ bias,
                                                float* __restrict__ C) {
    __shared__ float As[32][128];
    __shared__ float Bs[32][128];
    const int tid = threadIdx.x;
    const int tx = tid & 15, ty = tid >> 4;
    const int n_tile = blockIdx.x * 128;   // over D (8) - fastest, shares A tile
    const int m_tile = blockIdx.y * 128;   // over V (250)

    float acc[8][8];
    #pragma unroll
    for (int i = 0; i < 8; i++)
        #pragma unroll
        for (int j = 0; j < 8; j++) acc[i][j] = 0.f;

    const int lr = tid >> 1;          // 0..127 row within tile
    const int lk = (tid & 1) * 16;    // 0 or 16
    const float* Aptr = A  + (size_t)(m_tile + lr) * CD_ + lk;
    const float* Bptr = Bm + (size_t)(n_tile + lr) * CD_ + lk;

    for (int k0 = 0; k0 < CD_; k0 += 32) {
        float4 av[4], bv[4];
        #pragma unroll
        for (int q = 0; q < 4; q++) {
            av[q] = *(const float4*)(Aptr + k0 + q * 4);
            bv[q] = *(const float4*)(Bptr + k0 + q * 4);
        }
        __syncthreads();   // previous tile fully consumed
        #pragma unroll
        for (int q = 0; q < 4; q++) {
            As[lk+q*4+0][lr] = av[q].x; As[lk+q*4+1][lr] = av[q].y;
            As[lk+q*4+2][lr] = av[q].z; As[lk+q*4+3][lr] = av[q].w;
            Bs[lk+q*4+0][lr] = bv[q].x; Bs[lk+q*4+1][lr] = bv[q].y;
            Bs[lk+q*4+2][lr] = bv[q].z; Bs[lk+q*4+3][lr] = bv[q].w;
        }
        __syncthreads();
        #pragma unroll
        for (int kk = 0; kk < 32; kk++) {
            float4 a0 = *(const float4*)&As[kk][ty*8];
            float4 a1 = *(const float4*)&As[kk][ty*8+4];
            float4 b0 = *(const float4*)&Bs[kk][tx*8];
            float4 b1 = *(const float4*)&Bs[kk][tx*8+4];
            float a[8] = {a0.x,a0.y,a0.z,a0.w,a1.x,a1.y,a1.z,a1.w};
            float b[8] = {b0.x,b0.y,b0.z,b0.w,b1.x,b1.y,b1.z,b1.w};
            #pragma unroll
            for (int i = 0; i < 8; i++)
                #pragma unroll
                for (int j = 0; j < 8; j++)
                    acc[i][j] = fmaf(a[i], b[j], acc[i][j]);
        }
    }

    const int m0 = m_tile + ty * 8, n0 = n_tile + tx * 8;
    float bv0[8];
    #pragma unroll
    for (int j = 0; j < 8; j++) bv0[j] = bias[n0 + j];
    #pragma unroll
    for (int i = 0; i < 8; i++) {
        float4 r0 = {acc[i][0]+bv0[0], acc[i][1]+bv0[1], acc[i][2]+bv0[2], acc[i][3]+bv0[3]};
        float4 r1 = {acc[i][4]+bv0[4], acc[i][5]+bv0[5], acc[i][6]+bv0[6], acc[i][7]+bv0[7]};
        *(float4*)(C + (size_t)(m0+i)*D_ + n0)     = r0;
        *(float4*)(C + (size_t)(m0+i)*D_ + n0 + 4) = r1;
    }
}

// ---------------------------------------------------------------------------
// Row L2-norm reciprocal of proj: ninv[v] = 1/max(||proj_v||, eps)
// ---------------------------------------------------------------------------
__global__ __launch_bounds__(256) void vq_norms(const float* __restrict__ P,
                                                float* __restrict__ ninv) {
    const int row  = blockIdx.x * 4 + (threadIdx.x >> 6);
    const int lane = threadIdx.x & 63;
    const float* p = P + (size_t)row * D_;
    float s = 0.f;
    #pragma unroll
    for (int q = 0; q < 4; q++) {
        float4 v = *(const float4*)(p + q * 256 + lane * 4);
        s += v.x*v.x + v.y*v.y + v.z*v.z + v.w*v.w;
    }
    #pragma unroll
    for (int off = 32; off >= 1; off >>= 1) s += __shfl_down(s, off);
    if (lane == 0) ninv[row] = 1.0f / fmaxf(sqrtf(s), 1e-12f);
}

// ---------------------------------------------------------------------------
// enc[b*T+t][d] = z[b][d][t]   (64x64 LDS tile transpose per b)
// tile[x][y] holds z[b, d0+x, t0+y]; transposed read is tile[lane][tt]
// (pad 65 keeps the strided read conflict-free: addr = lane*65+tt)
// ---------------------------------------------------------------------------
__global__ __launch_bounds__(256) void vq_transpose(const float* __restrict__ z,
                                                    float* __restrict__ enc) {
    __shared__ float tile[64][65];
    const int b = blockIdx.z, t0 = blockIdx.x * 64, d0 = blockIdx.y * 64;
    const int lane = threadIdx.x & 63, sub = threadIdx.x >> 6;
    for (int dd = sub; dd < 64; dd += 4)
        tile[dd][lane] = z[((size_t)b * D_ + d0 + dd) * T_ + t0 + lane];
    __syncthreads();
    for (int tt = sub; tt < 64; tt += 4)
        enc[(size_t)(b * T_ + t0 + tt) * D_ + d0 + lane] = tile[lane][tt];
}

// ---------------------------------------------------------------------------
// GEMM2: S[i][v] = enc_i . proj_v, scaled by ninv[v]; per-tile argmax partials
// 128x128 tile, BK=32, K=1024. Deterministic (no atomics).
// ---------------------------------------------------------------------------
__global__ __launch_bounds__(256) void vq_gemm2(const float* __restrict__ E,
                                                const float* __restrict__ P,
                                                const float* __restrict__ ninv,
                                                float* __restrict__ pmax,
                                                int* __restrict__ pidx) {
    __shared__ float As[32][128];
    __shared__ float Bs[32][128];
    __shared__ float redv[128][17];
    __shared__ int   redi[128][17];
    const int tid = threadIdx.x;
    const int tx = tid & 15, ty = tid >> 4;
    const int m_tile = blockIdx.x * 128;   // over rows (16) - fastest, shares P tile
    const int n_tile = blockIdx.y * 128;   // over V (250)

    float acc[8][8];
    #pragma unroll
    for (int i = 0; i < 8; i++)
        #pragma unroll
        for (int j = 0; j < 8; j++) acc[i][j] = 0.f;

    const int lr = tid >> 1;
    const int lk = (tid & 1) * 16;
    const float* Eptr = E + (size_t)(m_tile + lr) * D_ + lk;
    const float* Pptr = P + (size_t)(n_tile + lr) * D_ + lk;

    for (int k0 = 0; k0 < D_; k0 += 32) {
        float4 av[4], bv[4];
        #pragma unroll
        for (int q = 0; q < 4; q++) {
            av[q] = *(const float4*)(Eptr + k0 + q * 4);
            bv[q] = *(const float4*)(Pptr + k0 + q * 4);
        }
        __syncthreads();
        #pragma unroll
        for (int q = 0; q < 4; q++) {
            As[lk+q*4+0][lr] = av[q].x; As[lk+q*4+1][lr] = av[q].y;
            As[lk+q*4+2][lr] = av[q].z; As[lk+q*4+3][lr] = av[q].w;
            Bs[lk+q*4+0][lr] = bv[q].x; Bs[lk+q*4+1][lr] = bv[q].y;
            Bs[lk+q*4+2][lr] = bv[q].z; Bs[lk+q*4+3][lr] = bv[q].w;
        }
        __syncthreads();
        #pragma unroll
        for (int kk = 0; kk < 32; kk++) {
            float4 a0 = *(const float4*)&As[kk][ty*8];
            float4 a1 = *(const float4*)&As[kk][ty*8+4];
            float4 b0 = *(const float4*)&Bs[kk][tx*8];
            float4 b1 = *(const float4*)&Bs[kk][tx*8+4];
            float a[8] = {a0.x,a0.y,a0.z,a0.w,a1.x,a1.y,a1.z,a1.w};
            float b[8] = {b0.x,b0.y,b0.z,b0.w,b1.x,b1.y,b1.z,b1.w};
            #pragma unroll
            for (int i = 0; i < 8; i++)
                #pragma unroll
                for (int j = 0; j < 8; j++)
                    acc[i][j] = fmaf(a[i], b[j], acc[i][j]);
        }
    }

    // epilogue: scaled argmax; ties -> smallest v (ascending scan, strict >)
    const int n0 = n_tile + tx * 8;
    float nv[8];
    #pragma unroll
    for (int j = 0; j < 8; j++) nv[j] = ninv[n0 + j];
    #pragma unroll
    for (int i = 0; i < 8; i++) {
        const int rl = ty * 8 + i;
        float best = -INFINITY; int bi = 0;
        #pragma unroll
        for (int j = 0; j < 8; j++) {
            float v = acc[i][j] * nv[j];
            if (v > best) { best = v; bi = n0 + j; }
        }
        redv[rl][tx] = best; redi[rl][tx] = bi;
    }
    __syncthreads();
    if (tid < 128) {
        float best = -INFINITY; int bi = 0;
        #pragma unroll
        for (int c = 0; c < 16; c++) {
            float v = redv[tid][c];
            if (v > best) { best = v; bi = redi[tid][c]; }
        }
        pmax[(size_t)(m_tile + tid) * VT + blockIdx.y] = best;
        pidx[(size_t)(m_tile + tid) * VT + blockIdx.y] = bi;
    }
}

// ---------------------------------------------------------------------------
// Merge per-tile argmax partials (in v-ascending order) -> final index
// ---------------------------------------------------------------------------
__global__ __launch_bounds__(256) void vq_argmerge(const float* __restrict__ pmax,
                                                   const int* __restrict__ pidx,
                                                   int* __restrict__ idxw,
                                                   float* __restrict__ outI) {
    const int i = blockIdx.x * 256 + threadIdx.x;
    if (i >= NR) return;
    float best = -INFINITY; int bi = 0;
    for (int c = 0; c < VT; c++) {
        float v = pmax[(size_t)i * VT + c];
        if (v > best) { best = v; bi = pidx[(size_t)i * VT + c]; }
    }
    idxw[i] = bi;
    outI[i] = (float)bi;
}

// ---------------------------------------------------------------------------
// Gather z_q = proj[idx] -> out0[b][d][t]; per-block partial sum of (z-z_q)^2
// ---------------------------------------------------------------------------
__global__ __launch_bounds__(256) void vq_gather(const float* __restrict__ proj,
                                                 const int* __restrict__ idxw,
                                                 const float* __restrict__ z,
                                                 float* __restrict__ out0,
                                                 float* __restrict__ lpart) {
    __shared__ float zq[64][65];
    __shared__ int idx_s[64];
    __shared__ float wsum[4];
    const int b = blockIdx.z, t0 = blockIdx.x * 64, d0 = blockIdx.y * 64;
    const int tid = threadIdx.x;
    const int lane = tid & 63, sub = tid >> 6;
    if (tid < 64) idx_s[tid] = idxw[b * T_ + t0 + tid];
    __syncthreads();
    for (int tt = sub; tt < 64; tt += 4)
        zq[tt][lane] = proj[(size_t)idx_s[tt] * D_ + d0 + lane];
    __syncthreads();
    float lacc = 0.f;
    for (int dd = sub; dd < 64; dd += 4) {
        const size_t base = ((size_t)b * D_ + d0 + dd) * T_ + t0 + lane;
        float q  = zq[lane][dd];
        float zv = z[base];
        out0[base] = q;
        float dv = zv - q;
        lacc += dv * dv;
    }
    #pragma unroll
    for (int off = 32; off >= 1; off >>= 1) lacc += __shfl_down(lacc, off);
    if (lane == 0) wsum[sub] = lacc;
    __syncthreads();
    if (tid == 0) {
        float s = wsum[0] + wsum[1] + wsum[2] + wsum[3];
        lpart[(blockIdx.z * 16 + blockIdx.y) * 8 + blockIdx.x] = s;
    }
}

// ---------------------------------------------------------------------------
// Final deterministic loss reduction: commitment == codebook numerically
// ---------------------------------------------------------------------------
__global__ void vq_loss(const float* __restrict__ lpart, float* __restrict__ outL) {
    const int b = threadIdx.x;
    if (b >= B_) return;
    float s = 0.f;
    for (int q = 0; q < 128; q++) s += lpart[b * 128 + q];
    s /= (float)(D_ * T_);
    outL[b]       = s;   // commitment_loss
    outL[B_ + b]  = s;   // codebook_loss
}

// ---------------------------------------------------------------------------
extern "C" void kernel_launch(void* const* d_in, const int* in_sizes, int n_in,
                              void* d_out, int out_size, void* d_ws, size_t ws_size,
                              hipStream_t stream) {
    const float* z        = (const float*)d_in[0];   // [B, D, T]
    const float* codebook = (const float*)d_in[1];   // [V, CD]
    const float* cb_w     = (const float*)d_in[2];   // [D, CD]
    const float* cb_b     = (const float*)d_in[3];   // [D]

    float* out0 = (float*)d_out;            // z_q_st  [B, D, T]
    float* outI = out0 + (size_t)B_*D_*T_;  // indices [B, T] (as float)
    float* outL = outI + NR;                // losses  [2*B]

    float* proj = (float*)d_ws;                       // V*D
    float* enc  = proj + (size_t)V_ * D_;             // NR*D
    float* ninv = enc  + (size_t)NR * D_;             // V
    float* pmax = ninv + V_;                          // NR*VT
    int*   pidx = (int*)(pmax + (size_t)NR * VT);     // NR*VT
    int*   idxw = pidx + (size_t)NR * VT;             // NR
    float* lpart = (float*)(idxw + NR);               // 512

    vq_gemm1<<<dim3(D_/128, V_/128), 256, 0, stream>>>(codebook, cb_w, cb_b, proj);
    vq_norms<<<V_/4, 256, 0, stream>>>(proj, ninv);
    vq_transpose<<<dim3(T_/64, D_/64, B_), 256, 0, stream>>>(z, enc);
    vq_gemm2<<<dim3(NR/128, V_/128), 256, 0, stream>>>(enc, proj, ninv, pmax, pidx);
    vq_argmerge<<<NR/256, 256, 0, stream>>>(pmax, pidx, idxw, outI);
    vq_gather<<<dim3(T_/64, D_/64, B_), 256, 0, stream>>>(proj, idxw, z, out0, lpart);
    vq_loss<<<1, 64, 0, stream>>>(lpart, outL);
}

// Round 3
// 1634.163 us; speedup vs baseline: 3.8532x; 3.8532x over previous
//
#include <hip/hip_runtime.h>
#include <hip/hip_bf16.h>
#include <math.h>

#define B_  4
#define D_  1024
#define T_  512
#define V_  32000
#define CD_ 4096
#define NR  (B_*T_)          // 2048 rows
#define VT  (V_/128)         // 250 v-tiles

typedef __attribute__((ext_vector_type(8))) short short8v;  // 8 bf16 (4 VGPR)
typedef __attribute__((ext_vector_type(4))) float f32x4;    // MFMA acc

#define MFMA16(a,b,c) __builtin_amdgcn_mfma_f32_16x16x32_bf16((a),(b),(c),0,0,0)

__device__ __forceinline__ unsigned short f2bf(float f) {
    return __builtin_bit_cast(unsigned short, __float2bfloat16(f));  // RNE
}
__device__ __forceinline__ float bf2f(unsigned short u) {
    unsigned int v = ((unsigned int)u) << 16;
    return __builtin_bit_cast(float, v);
}
__device__ __forceinline__ void glds16(const unsigned short* g, unsigned short* l) {
    __builtin_amdgcn_global_load_lds(
        (const __attribute__((address_space(1))) unsigned int*)g,
        (__attribute__((address_space(3))) unsigned int*)l, 16, 0, 0);
}
// 8 f32 -> hi/lo bf16 packs (Ootomo split, RNE both)
__device__ __forceinline__ void cvt8(const float4& x, const float4& y,
                                     short8v& h, short8v& l) {
    float xs[8] = {x.x, x.y, x.z, x.w, y.x, y.y, y.z, y.w};
    #pragma unroll
    for (int e = 0; e < 8; ++e) {
        unsigned short hb = f2bf(xs[e]);
        h[e] = (short)hb;
        l[e] = (short)f2bf(xs[e] - bf2f(hb));
    }
}

// ===========================================================================
// MAIN PATH (split-bf16 MFMA)
// LDS layout per 16-row x 32-k subtile: chunk c (=lane) holds
// row (c&15), k (c>>4)*8..+7  -> 16B per chunk, linear chunk order.
// Staging (global_load_lds / ds_write) and ds_read_b128 both address
// chunk==lane -> conflict-free, and A/B share the same k-permutation.
// ===========================================================================

// cb_w f32 -> hi/lo planes
__global__ __launch_bounds__(256) void vq_cvt(const float* __restrict__ x,
                                              unsigned short* __restrict__ hi,
                                              unsigned short* __restrict__ lo,
                                              size_t n4) {
    size_t stride = (size_t)gridDim.x * 256;
    for (size_t i = blockIdx.x * 256 + threadIdx.x; i < n4; i += stride) {
        float4 v = *(const float4*)(x + 4 * i);
        float xs[4] = {v.x, v.y, v.z, v.w};
        ushort4 h, l;
        unsigned short* hp = (unsigned short*)&h;
        unsigned short* lp = (unsigned short*)&l;
        #pragma unroll
        for (int e = 0; e < 4; ++e) {
            hp[e] = f2bf(xs[e]);
            lp[e] = f2bf(xs[e] - bf2f(hp[e]));
        }
        *(ushort4*)(hi + 4 * i) = h;
        *(ushort4*)(lo + 4 * i) = l;
    }
}

// GEMM1: proj(hi,lo)[V][D] = codebook[V][CD](f32, split in-kernel)
//        @ w(hi,lo)[D][CD]^T + bias ; 3-pass Ootomo MFMA
__global__ __launch_bounds__(256) void vq_gemm1_mfma(
    const float* __restrict__ A,
    const unsigned short* __restrict__ Bhi, const unsigned short* __restrict__ Blo,
    const float* __restrict__ bias,
    unsigned short* __restrict__ Phi, unsigned short* __restrict__ Plo)
{
    __shared__ unsigned short smem[2][4][4096]; // [buf][Ahi,Alo,Bhi,Blo][8 subtiles*512]
    const int tid = threadIdx.x;
    const int lane = tid & 63, w = tid >> 6;
    const int wr = w >> 1, wc = w & 1;
    const int m_tile = blockIdx.y * 128;   // V
    const int n_tile = blockIdx.x * 128;   // D
    const int row16 = lane & 15, kg = lane >> 4;
    const int s0 = 2 * w, s1 = s0 + 1;
    const int lane8 = lane * 8, wr4 = wr * 4, wc4 = wc * 4;

    const float*          Ap0 = A   + (size_t)(m_tile + s0*16 + row16) * CD_ + kg*8;
    const float*          Ap1 = A   + (size_t)(m_tile + s1*16 + row16) * CD_ + kg*8;
    const unsigned short* Bp0 = Bhi + (size_t)(n_tile + s0*16 + row16) * CD_ + kg*8;
    const unsigned short* Bp1 = Bhi + (size_t)(n_tile + s1*16 + row16) * CD_ + kg*8;
    const unsigned short* Lp0 = Blo + (size_t)(n_tile + s0*16 + row16) * CD_ + kg*8;
    const unsigned short* Lp1 = Blo + (size_t)(n_tile + s1*16 + row16) * CD_ + kg*8;

    f32x4 acc[4][4];
    #pragma unroll
    for (int i = 0; i < 4; ++i)
        #pragma unroll
        for (int j = 0; j < 4; ++j) acc[i][j] = (f32x4){0.f, 0.f, 0.f, 0.f};

    float4 aw[4], al_[4];

    // prologue: A(0) -> regs -> LDS buf0 ; B(0) glds -> buf0 ; A(1) -> regs
    aw[0] = *(const float4*)(Ap0);     aw[1] = *(const float4*)(Ap0 + 4);
    aw[2] = *(const float4*)(Ap1);     aw[3] = *(const float4*)(Ap1 + 4);
    glds16(Bp0, (unsigned short*)&smem[0][2][s0*512]);
    glds16(Bp1, (unsigned short*)&smem[0][2][s1*512]);
    glds16(Lp0, (unsigned short*)&smem[0][3][s0*512]);
    glds16(Lp1, (unsigned short*)&smem[0][3][s1*512]);
    {
        short8v h0, l0, h1, l1;
        cvt8(aw[0], aw[1], h0, l0);
        cvt8(aw[2], aw[3], h1, l1);
        *(short8v*)&smem[0][0][s0*512 + lane8] = h0;
        *(short8v*)&smem[0][1][s0*512 + lane8] = l0;
        *(short8v*)&smem[0][0][s1*512 + lane8] = h1;
        *(short8v*)&smem[0][1][s1*512 + lane8] = l1;
    }
    aw[0] = *(const float4*)(Ap0 + 32); aw[1] = *(const float4*)(Ap0 + 36);
    aw[2] = *(const float4*)(Ap1 + 32); aw[3] = *(const float4*)(Ap1 + 36);
    __syncthreads();

    int cur = 0;
    const int NT = CD_ / 32;   // 128
    for (int t = 0; t < NT; ++t) {
        if (t + 1 < NT) {
            const size_t ko = (size_t)(t + 1) * 32;
            glds16(Bp0 + ko, (unsigned short*)&smem[cur^1][2][s0*512]);
            glds16(Bp1 + ko, (unsigned short*)&smem[cur^1][2][s1*512]);
            glds16(Lp0 + ko, (unsigned short*)&smem[cur^1][3][s0*512]);
            glds16(Lp1 + ko, (unsigned short*)&smem[cur^1][3][s1*512]);
            short8v h0, l0, h1, l1;
            cvt8(aw[0], aw[1], h0, l0);
            cvt8(aw[2], aw[3], h1, l1);
            *(short8v*)&smem[cur^1][0][s0*512 + lane8] = h0;
            *(short8v*)&smem[cur^1][1][s0*512 + lane8] = l0;
            *(short8v*)&smem[cur^1][0][s1*512 + lane8] = h1;
            *(short8v*)&smem[cur^1][1][s1*512 + lane8] = l1;
        }
        if (t + 2 < NT) {
            const size_t ko2 = (size_t)(t + 2) * 32;
            al_[0] = *(const float4*)(Ap0 + ko2);  al_[1] = *(const float4*)(Ap0 + ko2 + 4);
            al_[2] = *(const float4*)(Ap1 + ko2);  al_[3] = *(const float4*)(Ap1 + ko2 + 4);
        }
        short8v ah[4], av[4], bh[4], bl[4];
        #pragma unroll
        for (int f = 0; f < 4; ++f) {
            ah[f] = *(const short8v*)&smem[cur][0][(wr4+f)*512 + lane8];
            av[f] = *(const short8v*)&smem[cur][1][(wr4+f)*512 + lane8];
            bh[f] = *(const short8v*)&smem[cur][2][(wc4+f)*512 + lane8];
            bl[f] = *(const short8v*)&smem[cur][3][(wc4+f)*512 + lane8];
        }
        #pragma unroll
        for (int mf = 0; mf < 4; ++mf)
            #pragma unroll
            for (int nf = 0; nf < 4; ++nf) {
                acc[mf][nf] = MFMA16(ah[mf], bh[nf], acc[mf][nf]);
                acc[mf][nf] = MFMA16(ah[mf], bl[nf], acc[mf][nf]);
                acc[mf][nf] = MFMA16(av[mf], bh[nf], acc[mf][nf]);
            }
        __syncthreads();
        #pragma unroll
        for (int q = 0; q < 4; ++q) aw[q] = al_[q];
        cur ^= 1;
    }

    // epilogue: +bias, split to hi/lo planes.  C/D: col=lane&15, row=kg*4+r
    #pragma unroll
    for (int nf = 0; nf < 4; ++nf) {
        const int col = n_tile + wc*64 + nf*16 + row16;
        const float bv = bias[col];
        #pragma unroll
        for (int mf = 0; mf < 4; ++mf) {
            const int rbase = m_tile + wr*64 + mf*16 + kg*4;
            #pragma unroll
            for (int r = 0; r < 4; ++r) {
                float vv = acc[mf][nf][r] + bv;
                unsigned short h = f2bf(vv);
                unsigned short l = f2bf(vv - bf2f(h));
                size_t o = (size_t)(rbase + r) * D_ + col;
                Phi[o] = h; Plo[o] = l;
            }
        }
    }
}

// row-norm reciprocal from hi/lo planes
__global__ __launch_bounds__(256) void vq_norms_pl(const unsigned short* __restrict__ ph,
                                                   const unsigned short* __restrict__ pl,
                                                   float* __restrict__ ninv) {
    const int row  = blockIdx.x * 4 + (threadIdx.x >> 6);
    const int lane = threadIdx.x & 63;
    float s = 0.f;
    #pragma unroll
    for (int q = 0; q < 2; ++q) {
        size_t o = (size_t)row * D_ + q * 512 + lane * 8;
        short8v h = *(const short8v*)(ph + o);
        short8v l = *(const short8v*)(pl + o);
        #pragma unroll
        for (int e = 0; e < 8; ++e) {
            float x = bf2f((unsigned short)h[e]) + bf2f((unsigned short)l[e]);
            s += x * x;
        }
    }
    #pragma unroll
    for (int off = 32; off >= 1; off >>= 1) s += __shfl_down(s, off);
    if (lane == 0) ninv[row] = 1.0f / fmaxf(sqrtf(s), 1e-12f);
}

// z[b][d][t] -> enc hi/lo planes [b*T+t][d]
__global__ __launch_bounds__(256) void vq_transpose_cvt(const float* __restrict__ z,
                                                        unsigned short* __restrict__ ehi,
                                                        unsigned short* __restrict__ elo) {
    __shared__ float tile[64][65];
    const int b = blockIdx.z, t0 = blockIdx.x * 64, d0 = blockIdx.y * 64;
    const int lane = threadIdx.x & 63, sub = threadIdx.x >> 6;
    for (int dd = sub; dd < 64; dd += 4)
        tile[dd][lane] = z[((size_t)b * D_ + d0 + dd) * T_ + t0 + lane];
    __syncthreads();
    for (int tt = sub; tt < 64; tt += 4) {
        float v = tile[lane][tt];
        unsigned short h = f2bf(v);
        unsigned short l = f2bf(v - bf2f(h));
        size_t o = (size_t)(b * T_ + t0 + tt) * D_ + d0 + lane;
        ehi[o] = h; elo[o] = l;
    }
}

// GEMM2: scores enc x proj^T (split-bf16, 3-pass), fused scaled argmax
__global__ __launch_bounds__(256) void vq_gemm2_mfma(
    const unsigned short* __restrict__ Ehi, const unsigned short* __restrict__ Elo,
    const unsigned short* __restrict__ Phi, const unsigned short* __restrict__ Plo,
    const float* __restrict__ ninv,
    float* __restrict__ pmax, int* __restrict__ pidx)
{
    __shared__ unsigned short smem[2][4][4096];
    __shared__ float redv[2][128];
    __shared__ int   redi[2][128];
    const int tid = threadIdx.x;
    const int lane = tid & 63, w = tid >> 6;
    const int wr = w >> 1, wc = w & 1;
    const int m_tile = blockIdx.x * 128;   // rows (NR)
    const int n_tile = blockIdx.y * 128;   // V
    const int row16 = lane & 15, kg = lane >> 4;
    const int s0 = 2 * w, s1 = s0 + 1;
    const int lane8 = lane * 8, wr4 = wr * 4, wc4 = wc * 4;

    const unsigned short* Ap0 = Ehi + (size_t)(m_tile + s0*16 + row16) * D_ + kg*8;
    const unsigned short* Ap1 = Ehi + (size_t)(m_tile + s1*16 + row16) * D_ + kg*8;
    const unsigned short* Cp0 = Elo + (size_t)(m_tile + s0*16 + row16) * D_ + kg*8;
    const unsigned short* Cp1 = Elo + (size_t)(m_tile + s1*16 + row16) * D_ + kg*8;
    const unsigned short* Bp0 = Phi + (size_t)(n_tile + s0*16 + row16) * D_ + kg*8;
    const unsigned short* Bp1 = Phi + (size_t)(n_tile + s1*16 + row16) * D_ + kg*8;
    const unsigned short* Lp0 = Plo + (size_t)(n_tile + s0*16 + row16) * D_ + kg*8;
    const unsigned short* Lp1 = Plo + (size_t)(n_tile + s1*16 + row16) * D_ + kg*8;

    f32x4 acc[4][4];
    #pragma unroll
    for (int i = 0; i < 4; ++i)
        #pragma unroll
        for (int j = 0; j < 4; ++j) acc[i][j] = (f32x4){0.f, 0.f, 0.f, 0.f};

#define STG2(bb, ko) do { \
    glds16(Ap0 + (ko), (unsigned short*)&smem[bb][0][s0*512]); \
    glds16(Ap1 + (ko), (unsigned short*)&smem[bb][0][s1*512]); \
    glds16(Cp0 + (ko), (unsigned short*)&smem[bb][1][s0*512]); \
    glds16(Cp1 + (ko), (unsigned short*)&smem[bb][1][s1*512]); \
    glds16(Bp0 + (ko), (unsigned short*)&smem[bb][2][s0*512]); \
    glds16(Bp1 + (ko), (unsigned short*)&smem[bb][2][s1*512]); \
    glds16(Lp0 + (ko), (unsigned short*)&smem[bb][3][s0*512]); \
    glds16(Lp1 + (ko), (unsigned short*)&smem[bb][3][s1*512]); \
} while (0)

    STG2(0, 0);
    __syncthreads();
    int cur = 0;
    const int NT = D_ / 32;   // 32
    for (int t = 0; t < NT; ++t) {
        if (t + 1 < NT) STG2(cur^1, (size_t)(t + 1) * 32);
        short8v ah[4], av[4], bh[4], bl[4];
        #pragma unroll
        for (int f = 0; f < 4; ++f) {
            ah[f] = *(const short8v*)&smem[cur][0][(wr4+f)*512 + lane8];
            av[f] = *(const short8v*)&smem[cur][1][(wr4+f)*512 + lane8];
            bh[f] = *(const short8v*)&smem[cur][2][(wc4+f)*512 + lane8];
            bl[f] = *(const short8v*)&smem[cur][3][(wc4+f)*512 + lane8];
        }
        #pragma unroll
        for (int mf = 0; mf < 4; ++mf)
            #pragma unroll
            for (int nf = 0; nf < 4; ++nf) {
                acc[mf][nf] = MFMA16(ah[mf], bh[nf], acc[mf][nf]);
                acc[mf][nf] = MFMA16(ah[mf], bl[nf], acc[mf][nf]);
                acc[mf][nf] = MFMA16(av[mf], bh[nf], acc[mf][nf]);
            }
        __syncthreads();
        cur ^= 1;
    }
#undef STG2

    // scaled argmax; tie -> smallest v (matches np.argmax first-occurrence)
    float nv[4];
    #pragma unroll
    for (int nf = 0; nf < 4; ++nf) nv[nf] = ninv[n_tile + wc*64 + nf*16 + row16];
    #pragma unroll
    for (int mf = 0; mf < 4; ++mf) {
        #pragma unroll
        for (int r = 0; r < 4; ++r) {
            float best = -INFINITY; int bi = 0x7fffffff;
            #pragma unroll
            for (int nf = 0; nf < 4; ++nf) {
                float v = acc[mf][nf][r] * nv[nf];
                int ci = n_tile + wc*64 + nf*16 + row16;
                if (v > best || (v == best && ci < bi)) { best = v; bi = ci; }
            }
            #pragma unroll
            for (int m = 8; m >= 1; m >>= 1) {
                float ov = __shfl_xor(best, m, 16);
                int   oi = __shfl_xor(bi,   m, 16);
                if (ov > best || (ov == best && oi < bi)) { best = ov; bi = oi; }
            }
            if (row16 == 0) {
                int rl = wr*64 + mf*16 + kg*4 + r;
                redv[wc][rl] = best; redi[wc][rl] = bi;
            }
        }
    }
    __syncthreads();
    if (tid < 128) {
        float v0 = redv[0][tid], v1 = redv[1][tid];
        int   i0 = redi[0][tid], i1 = redi[1][tid];
        bool t1 = (v1 > v0) || (v1 == v0 && i1 < i0);
        size_t o = (size_t)(m_tile + tid) * VT + blockIdx.y;
        pmax[o] = t1 ? v1 : v0;
        pidx[o] = t1 ? i1 : i0;
    }
}

// gather from hi/lo planes + loss partials
__global__ __launch_bounds__(256) void vq_gather_pl(const unsigned short* __restrict__ ph,
                                                    const unsigned short* __restrict__ pl,
                                                    const int* __restrict__ idxw,
                                                    const float* __restrict__ z,
                                                    float* __restrict__ out0,
                                                    float* __restrict__ lpart) {
    __shared__ float zq[64][65];
    __shared__ int idx_s[64];
    __shared__ float wsum[4];
    const int b = blockIdx.z, t0 = blockIdx.x * 64, d0 = blockIdx.y * 64;
    const int tid = threadIdx.x;
    const int lane = tid & 63, sub = tid >> 6;
    if (tid < 64) idx_s[tid] = idxw[b * T_ + t0 + tid];
    __syncthreads();
    for (int tt = sub; tt < 64; tt += 4) {
        size_t o = (size_t)idx_s[tt] * D_ + d0 + lane;
        zq[tt][lane] = bf2f(ph[o]) + bf2f(pl[o]);
    }
    __syncthreads();
    float lacc = 0.f;
    for (int dd = sub; dd < 64; dd += 4) {
        const size_t base = ((size_t)b * D_ + d0 + dd) * T_ + t0 + lane;
        float q = zq[lane][dd];
        float zv = z[base];
        out0[base] = q;
        float dv = zv - q;
        lacc += dv * dv;
    }
    #pragma unroll
    for (int off = 32; off >= 1; off >>= 1) lacc += __shfl_down(lacc, off);
    if (lane == 0) wsum[sub] = lacc;
    __syncthreads();
    if (tid == 0)
        lpart[(blockIdx.z * 16 + blockIdx.y) * 8 + blockIdx.x] =
            wsum[0] + wsum[1] + wsum[2] + wsum[3];
}

// ---- shared by both paths -------------------------------------------------
__global__ __launch_bounds__(256) void vq_argmerge(const float* __restrict__ pmax,
                                                   const int* __restrict__ pidx,
                                                   int* __restrict__ idxw,
                                                   float* __restrict__ outI) {
    const int i = blockIdx.x * 256 + threadIdx.x;
    if (i >= NR) return;
    float best = -INFINITY; int bi = 0;
    for (int c = 0; c < VT; c++) {
        float v = pmax[(size_t)i * VT + c];
        if (v > best) { best = v; bi = pidx[(size_t)i * VT + c]; }
    }
    idxw[i] = bi;
    outI[i] = (float)bi;
}

__global__ void vq_loss(const float* __restrict__ lpart, float* __restrict__ outL) {
    const int b = threadIdx.x;
    if (b >= B_) return;
    float s = 0.f;
    for (int q = 0; q < 128; q++) s += lpart[b * 128 + q];
    s /= (float)(D_ * T_);
    outL[b]      = s;
    outL[B_ + b] = s;
}

// ===========================================================================
// LEGACY FALLBACK (round-2 f32 path, used only if ws_size is too small)
// ===========================================================================
__global__ __launch_bounds__(256) void vq_gemm1(const float* __restrict__ A,
                                                const float* __restrict__ Bm,
                                                const float* __restrict__ bias,
                                                float* __restrict__ C) {
    __shared__ float As[32][128];
    __shared__ float Bs[32][128];
    const int tid = threadIdx.x;
    const int tx = tid & 15, ty = tid >> 4;
    const int n_tile = blockIdx.x * 128;
    const int m_tile = blockIdx.y * 128;
    float acc[8][8];
    #pragma unroll
    for (int i = 0; i < 8; i++)
        #pragma unroll
        for (int j = 0; j < 8; j++) acc[i][j] = 0.f;
    const int lr = tid >> 1;
    const int lk = (tid & 1) * 16;
    const float* Aptr = A  + (size_t)(m_tile + lr) * CD_ + lk;
    const float* Bptr = Bm + (size_t)(n_tile + lr) * CD_ + lk;
    for (int k0 = 0; k0 < CD_; k0 += 32) {
        float4 av[4], bv[4];
        #pragma unroll
        for (int q = 0; q < 4; q++) {
            av[q] = *(const float4*)(Aptr + k0 + q * 4);
            bv[q] = *(const float4*)(Bptr + k0 + q * 4);
        }
        __syncthreads();
        #pragma unroll
        for (int q = 0; q < 4; q++) {
            As[lk+q*4+0][lr] = av[q].x; As[lk+q*4+1][lr] = av[q].y;
            As[lk+q*4+2][lr] = av[q].z; As[lk+q*4+3][lr] = av[q].w;
            Bs[lk+q*4+0][lr] = bv[q].x; Bs[lk+q*4+1][lr] = bv[q].y;
            Bs[lk+q*4+2][lr] = bv[q].z; Bs[lk+q*4+3][lr] = bv[q].w;
        }
        __syncthreads();
        #pragma unroll
        for (int kk = 0; kk < 32; kk++) {
            float4 a0 = *(const float4*)&As[kk][ty*8];
            float4 a1 = *(const float4*)&As[kk][ty*8+4];
            float4 b0 = *(const float4*)&Bs[kk][tx*8];
            float4 b1 = *(const float4*)&Bs[kk][tx*8+4];
            float a[8] = {a0.x,a0.y,a0.z,a0.w,a1.x,a1.y,a1.z,a1.w};
            float b[8] = {b0.x,b0.y,b0.z,b0.w,b1.x,b1.y,b1.z,b1.w};
            #pragma unroll
            for (int i = 0; i < 8; i++)
                #pragma unroll
                for (int j = 0; j < 8; j++)
                    acc[i][j] = fmaf(a[i], b[j], acc[i][j]);
        }
    }
    const int m0 = m_tile + ty * 8, n0 = n_tile + tx * 8;
    float bv0[8];
    #pragma unroll
    for (int j = 0; j < 8; j++) bv0[j] = bias[n0 + j];
    #pragma unroll
    for (int i = 0; i < 8; i++) {
        float4 r0 = {acc[i][0]+bv0[0], acc[i][1]+bv0[1], acc[i][2]+bv0[2], acc[i][3]+bv0[3]};
        float4 r1 = {acc[i][4]+bv0[4], acc[i][5]+bv0[5], acc[i][6]+bv0[6], acc[i][7]+bv0[7]};
        *(float4*)(C + (size_t)(m0+i)*D_ + n0)     = r0;
        *(float4*)(C + (size_t)(m0+i)*D_ + n0 + 4) = r1;
    }
}

__global__ __launch_bounds__(256) void vq_norms(const float* __restrict__ P,
                                                float* __restrict__ ninv) {
    const int row  = blockIdx.x * 4 + (threadIdx.x >> 6);
    const int lane = threadIdx.x & 63;
    const float* p = P + (size_t)row * D_;
    float s = 0.f;
    #pragma unroll
    for (int q = 0; q < 4; q++) {
        float4 v = *(const float4*)(p + q * 256 + lane * 4);
        s += v.x*v.x + v.y*v.y + v.z*v.z + v.w*v.w;
    }
    #pragma unroll
    for (int off = 32; off >= 1; off >>= 1) s += __shfl_down(s, off);
    if (lane == 0) ninv[row] = 1.0f / fmaxf(sqrtf(s), 1e-12f);
}

__global__ __launch_bounds__(256) void vq_transpose(const float* __restrict__ z,
                                                    float* __restrict__ enc) {
    __shared__ float tile[64][65];
    const int b = blockIdx.z, t0 = blockIdx.x * 64, d0 = blockIdx.y * 64;
    const int lane = threadIdx.x & 63, sub = threadIdx.x >> 6;
    for (int dd = sub; dd < 64; dd += 4)
        tile[dd][lane] = z[((size_t)b * D_ + d0 + dd) * T_ + t0 + lane];
    __syncthreads();
    for (int tt = sub; tt < 64; tt += 4)
        enc[(size_t)(b * T_ + t0 + tt) * D_ + d0 + lane] = tile[lane][tt];
}

__global__ __launch_bounds__(256) void vq_gemm2(const float* __restrict__ E,
                                                const float* __restrict__ P,
                                                const float* __restrict__ ninv,
                                                float* __restrict__ pmax,
                                                int* __restrict__ pidx) {
    __shared__ float As[32][128];
    __shared__ float Bs[32][128];
    __shared__ float redv[128][17];
    __shared__ int   redi[128][17];
    const int tid = threadIdx.x;
    const int tx = tid & 15, ty = tid >> 4;
    const int m_tile = blockIdx.x * 128;
    const int n_tile = blockIdx.y * 128;
    float acc[8][8];
    #pragma unroll
    for (int i = 0; i < 8; i++)
        #pragma unroll
        for (int j = 0; j < 8; j++) acc[i][j] = 0.f;
    const int lr = tid >> 1;
    const int lk = (tid & 1) * 16;
    const float* Eptr = E + (size_t)(m_tile + lr) * D_ + lk;
    const float* Pptr = P + (size_t)(n_tile + lr) * D_ + lk;
    for (int k0 = 0; k0 < D_; k0 += 32) {
        float4 av[4], bv[4];
        #pragma unroll
        for (int q = 0; q < 4; q++) {
            av[q] = *(const float4*)(Eptr + k0 + q * 4);
            bv[q] = *(const float4*)(Pptr + k0 + q * 4);
        }
        __syncthreads();
        #pragma unroll
        for (int q = 0; q < 4; q++) {
            As[lk+q*4+0][lr] = av[q].x; As[lk+q*4+1][lr] = av[q].y;
            As[lk+q*4+2][lr] = av[q].z; As[lk+q*4+3][lr] = av[q].w;
            Bs[lk+q*4+0][lr] = bv[q].x; Bs[lk+q*4+1][lr] = bv[q].y;
            Bs[lk+q*4+2][lr] = bv[q].z; Bs[lk+q*4+3][lr] = bv[q].w;
        }
        __syncthreads();
        #pragma unroll
        for (int kk = 0; kk < 32; kk++) {
            float4 a0 = *(const float4*)&As[kk][ty*8];
            float4 a1 = *(const float4*)&As[kk][ty*8+4];
            float4 b0 = *(const float4*)&Bs[kk][tx*8];
            float4 b1 = *(const float4*)&Bs[kk][tx*8+4];
            float a[8] = {a0.x,a0.y,a0.z,a0.w,a1.x,a1.y,a1.z,a1.w};
            float b[8] = {b0.x,b0.y,b0.z,b0.w,b1.x,b1.y,b1.z,b1.w};
            #pragma unroll
            for (int i = 0; i < 8; i++)
                #pragma unroll
                for (int j = 0; j < 8; j++)
                    acc[i][j] = fmaf(a[i], b[j], acc[i][j]);
        }
    }
    const int n0 = n_tile + tx * 8;
    float nv[8];
    #pragma unroll
    for (int j = 0; j < 8; j++) nv[j] = ninv[n0 + j];
    #pragma unroll
    for (int i = 0; i < 8; i++) {
        const int rl = ty * 8 + i;
        float best = -INFINITY; int bi = 0;
        #pragma unroll
        for (int j = 0; j < 8; j++) {
            float v = acc[i][j] * nv[j];
            if (v > best) { best = v; bi = n0 + j; }
        }
        redv[rl][tx] = best; redi[rl][tx] = bi;
    }
    __syncthreads();
    if (tid < 128) {
        float best = -INFINITY; int bi = 0;
        #pragma unroll
        for (int c = 0; c < 16; c++) {
            float v = redv[tid][c];
            if (v > best) { best = v; bi = redi[tid][c]; }
        }
        pmax[(size_t)(m_tile + tid) * VT + blockIdx.y] = best;
        pidx[(size_t)(m_tile + tid) * VT + blockIdx.y] = bi;
    }
}

__global__ __launch_bounds__(256) void vq_gather(const float* __restrict__ proj,
                                                 const int* __restrict__ idxw,
                                                 const float* __restrict__ z,
                                                 float* __restrict__ out0,
                                                 float* __restrict__ lpart) {
    __shared__ float zq[64][65];
    __shared__ int idx_s[64];
    __shared__ float wsum[4];
    const int b = blockIdx.z, t0 = blockIdx.x * 64, d0 = blockIdx.y * 64;
    const int tid = threadIdx.x;
    const int lane = tid & 63, sub = tid >> 6;
    if (tid < 64) idx_s[tid] = idxw[b * T_ + t0 + tid];
    __syncthreads();
    for (int tt = sub; tt < 64; tt += 4)
        zq[tt][lane] = proj[(size_t)idx_s[tt] * D_ + d0 + lane];
    __syncthreads();
    float lacc = 0.f;
    for (int dd = sub; dd < 64; dd += 4) {
        const size_t base = ((size_t)b * D_ + d0 + dd) * T_ + t0 + lane;
        float q  = zq[lane][dd];
        float zv = z[base];
        out0[base] = q;
        float dv = zv - q;
        lacc += dv * dv;
    }
    #pragma unroll
    for (int off = 32; off >= 1; off >>= 1) lacc += __shfl_down(lacc, off);
    if (lane == 0) wsum[sub] = lacc;
    __syncthreads();
    if (tid == 0)
        lpart[(blockIdx.z * 16 + blockIdx.y) * 8 + blockIdx.x] =
            wsum[0] + wsum[1] + wsum[2] + wsum[3];
}

// ===========================================================================
extern "C" void kernel_launch(void* const* d_in, const int* in_sizes, int n_in,
                              void* d_out, int out_size, void* d_ws, size_t ws_size,
                              hipStream_t stream) {
    const float* z        = (const float*)d_in[0];   // [B, D, T]
    const float* codebook = (const float*)d_in[1];   // [V, CD]
    const float* cb_w     = (const float*)d_in[2];   // [D, CD]
    const float* cb_b     = (const float*)d_in[3];   // [D]

    float* out0 = (float*)d_out;
    float* outI = out0 + (size_t)B_*D_*T_;
    float* outL = outI + NR;

    // main-path workspace layout
    char* p = (char*)d_ws;
    auto alloc = [&](size_t bytes) { char* r = p; p += (bytes + 255) & ~(size_t)255; return r; };
    unsigned short* w_hi = (unsigned short*)alloc((size_t)D_ * CD_ * 2);
    unsigned short* w_lo = (unsigned short*)alloc((size_t)D_ * CD_ * 2);
    unsigned short* p_hi = (unsigned short*)alloc((size_t)V_ * D_ * 2);
    unsigned short* p_lo = (unsigned short*)alloc((size_t)V_ * D_ * 2);
    unsigned short* e_hi = (unsigned short*)alloc((size_t)NR * D_ * 2);
    unsigned short* e_lo = (unsigned short*)alloc((size_t)NR * D_ * 2);
    float* ninv  = (float*)alloc((size_t)V_ * 4);
    float* pmax  = (float*)alloc((size_t)NR * VT * 4);
    int*   pidx  = (int*)  alloc((size_t)NR * VT * 4);
    int*   idxw  = (int*)  alloc((size_t)NR * 4);
    float* lpart = (float*)alloc((size_t)2048 * 4);
    size_t need = (size_t)(p - (char*)d_ws);

    if (ws_size >= need) {
        vq_cvt<<<1024, 256, 0, stream>>>(cb_w, w_hi, w_lo, (size_t)D_ * CD_ / 4);
        vq_gemm1_mfma<<<dim3(D_/128, V_/128), 256, 0, stream>>>(codebook, w_hi, w_lo,
                                                                cb_b, p_hi, p_lo);
        vq_norms_pl<<<V_/4, 256, 0, stream>>>(p_hi, p_lo, ninv);
        vq_transpose_cvt<<<dim3(T_/64, D_/64, B_), 256, 0, stream>>>(z, e_hi, e_lo);
        vq_gemm2_mfma<<<dim3(NR/128, V_/128), 256, 0, stream>>>(e_hi, e_lo, p_hi, p_lo,
                                                                ninv, pmax, pidx);
        vq_argmerge<<<NR/256, 256, 0, stream>>>(pmax, pidx, idxw, outI);
        vq_gather_pl<<<dim3(T_/64, D_/64, B_), 256, 0, stream>>>(p_hi, p_lo, idxw, z,
                                                                 out0, lpart);
        vq_loss<<<1, 64, 0, stream>>>(lpart, outL);
    } else {
        // legacy f32 path (round-2 layout)
        float* proj  = (float*)d_ws;                          // V*D
        float* enc   = proj + (size_t)V_ * D_;                // NR*D
        float* ninv2 = enc  + (size_t)NR * D_;                // V
        float* pmax2 = ninv2 + V_;                            // NR*VT
        int*   pidx2 = (int*)(pmax2 + (size_t)NR * VT);       // NR*VT
        int*   idxw2 = pidx2 + (size_t)NR * VT;               // NR
        float* lpart2 = (float*)(idxw2 + NR);                 // 512

        vq_gemm1<<<dim3(D_/128, V_/128), 256, 0, stream>>>(codebook, cb_w, cb_b, proj);
        vq_norms<<<V_/4, 256, 0, stream>>>(proj, ninv2);
        vq_transpose<<<dim3(T_/64, D_/64, B_), 256, 0, stream>>>(z, enc);
        vq_gemm2<<<dim3(NR/128, V_/128), 256, 0, stream>>>(enc, proj, ninv2, pmax2, pidx2);
        vq_argmerge<<<NR/256, 256, 0, stream>>>(pmax2, pidx2, idxw2, outI);
        vq_gather<<<dim3(T_/64, D_/64, B_), 256, 0, stream>>>(proj, idxw2, z, out0, lpart2);
        vq_loss<<<1, 64, 0, stream>>>(lpart2, outL);
    }
}

// Round 4
// 1558.950 us; speedup vs baseline: 4.0391x; 1.0482x over previous
//
#include <hip/hip_runtime.h>
#include <hip/hip_bf16.h>
#include <math.h>

#define B_  4
#define D_  1024
#define T_  512
#define V_  32000
#define CD_ 4096
#define NR  (B_*T_)          // 2048 rows
#define VT2 (V_/256)         // 125 v-tiles (256-wide)

typedef __attribute__((ext_vector_type(8))) short short8v;  // 8 bf16 (4 VGPR)
typedef __attribute__((ext_vector_type(4))) float f32x4;    // MFMA acc

#define MFMA16(a,b,c) __builtin_amdgcn_mfma_f32_16x16x32_bf16((a),(b),(c),0,0,0)

#define ASM_VMCNT8() asm volatile("s_waitcnt vmcnt(8)" ::: "memory")
#define ASM_VMCNT0() asm volatile("s_waitcnt vmcnt(0)" ::: "memory")
#define ASM_LGKM0()  asm volatile("s_waitcnt lgkmcnt(0)" ::: "memory")
#define BARRIER()    do { asm volatile("" ::: "memory");            \
                          __builtin_amdgcn_s_barrier();             \
                          __builtin_amdgcn_sched_barrier(0); } while (0)

__device__ __forceinline__ unsigned short f2bf(float f) {
    return __builtin_bit_cast(unsigned short, __float2bfloat16(f));  // RNE
}
__device__ __forceinline__ float bf2f(unsigned short u) {
    unsigned int v = ((unsigned int)u) << 16;
    return __builtin_bit_cast(float, v);
}
__device__ __forceinline__ void glds16(const unsigned short* g, unsigned short* l) {
    __builtin_amdgcn_global_load_lds(
        (const __attribute__((address_space(1))) unsigned int*)g,
        (__attribute__((address_space(3))) unsigned int*)l, 16, 0, 0);
}
__device__ __forceinline__ void cvt8(const float4& x, const float4& y,
                                     short8v& h, short8v& l) {
    float xs[8] = {x.x, x.y, x.z, x.w, y.x, y.y, y.z, y.w};
    #pragma unroll
    for (int e = 0; e < 8; ++e) {
        unsigned short hb = f2bf(xs[e]);
        h[e] = (short)hb;
        l[e] = (short)f2bf(xs[e] - bf2f(hb));
    }
}
// bijective XCD swizzle (m204 form), valid for any nwg
__device__ __forceinline__ int xcd_swz(int wg, int nwg) {
    int q = nwg >> 3, r = nwg & 7;
    int x = wg & 7, o = wg >> 3;
    return (x < r ? x * (q + 1) : r * (q + 1) + (x - r) * q) + o;
}

// ---------------------------------------------------------------------------
// f32 -> hi/lo bf16 planes (Ootomo split, RNE both)
// ---------------------------------------------------------------------------
__global__ __launch_bounds__(256) void vq_cvt(const float* __restrict__ x,
                                              unsigned short* __restrict__ hi,
                                              unsigned short* __restrict__ lo,
                                              size_t n4) {
    size_t stride = (size_t)gridDim.x * 256;
    for (size_t i = (size_t)blockIdx.x * 256 + threadIdx.x; i < n4; i += stride) {
        float4 v = *(const float4*)(x + 4 * i);
        float xs[4] = {v.x, v.y, v.z, v.w};
        ushort4 h, l;
        unsigned short* hp = (unsigned short*)&h;
        unsigned short* lp = (unsigned short*)&l;
        #pragma unroll
        for (int e = 0; e < 4; ++e) {
            hp[e] = f2bf(xs[e]);
            lp[e] = f2bf(xs[e] - bf2f(hp[e]));
        }
        *(ushort4*)(hi + 4 * i) = h;
        *(ushort4*)(lo + 4 * i) = l;
    }
}

// ===========================================================================
// 8-wave 256x256 phase-split GEMM core (T3+T4+T5), BK=32, 3-pass split-bf16.
// LDS per plane per K-step: 16 subtiles (16 rows x 32 k), chunk c=lane holds
// row (c&15), k (c>>4)*8..+7 -> glds16 linear AND ds_read_b128 conflict-free
// (measured 0 bank conflicts in round 3).
// Wave grid 2Mx4N: wave w -> wr=w>>2 (128-row half), wc=w&3 (64-col quarter).
// glds: wave w stages plane w>>1, subtiles (w&1)*8 .. +7 (8 units/thread).
// Counted vmcnt(8): next step's 8 loads in flight across the whole step.
// ===========================================================================
#define GEMM_CORE_8P(KD)                                                      \
    f32x4 acc[8][4];                                                          \
    _Pragma("unroll")                                                         \
    for (int i = 0; i < 8; ++i)                                               \
        _Pragma("unroll")                                                     \
        for (int j = 0; j < 4; ++j) acc[i][j] = (f32x4){0.f, 0.f, 0.f, 0.f};  \
    const int lane = threadIdx.x & 63, w = threadIdx.x >> 6;                  \
    const int wr = w >> 2, wc = w & 3;                                        \
    const int r16 = lane & 15, kg = lane >> 4;                                \
    const int lane8 = lane * 8, wr8 = wr * 8, wc4 = wc * 4;                   \
    const int pw = w >> 1;                                                    \
    const unsigned short* gplane = (pw == 0) ? Ahp : (pw == 1) ? Alp          \
                                   : (pw == 2) ? Bhp : Blp;                   \
    const int baseRow = (pw < 2 ? mt : nt) + (w & 1) * 128 + r16;             \
    const unsigned short* gsrc = gplane + (size_t)baseRow * (KD) + kg * 8;    \
    unsigned short* lb0 = &smem[0][pw][(w & 1) * 4096 + lane8];               \
    unsigned short* lb1 = &smem[1][pw][(w & 1) * 4096 + lane8];               \
    /* prologue: stage step 0 */                                              \
    _Pragma("unroll")                                                         \
    for (int q = 0; q < 8; ++q)                                               \
        glds16(gsrc + (size_t)q * 16 * (KD), lb0 + q * 512);                  \
    ASM_VMCNT0();                                                             \
    BARRIER();                                                                \
    const int NT = (KD) / 32;                                                 \
    for (int t = 0; t < NT; ++t) {                                            \
        const int cur = t & 1;                                                \
        /* phase 0: stage t+1, counted wait, validity barrier */              \
        if (t + 1 < NT) {                                                     \
            unsigned short* lb = cur ? lb0 : lb1;                             \
            const size_t kof = (size_t)(t + 1) * 32;                          \
            _Pragma("unroll")                                                 \
            for (int q = 0; q < 8; ++q)                                       \
                glds16(gsrc + kof + (size_t)q * 16 * (KD), lb + q * 512);     \
            ASM_VMCNT8();                                                     \
        } else {                                                              \
            ASM_VMCNT0();                                                     \
        }                                                                     \
        BARRIER();                                                            \
        short8v bh[4], bl[4];                                                 \
        _Pragma("unroll")                                                     \
        for (int nf = 0; nf < 4; ++nf) {                                      \
            bh[nf] = *(const short8v*)&smem[cur][2][(wc4 + nf) * 512 + lane8];\
            bl[nf] = *(const short8v*)&smem[cur][3][(wc4 + nf) * 512 + lane8];\
        }                                                                     \
        {                                                                     \
            short8v a0h = *(const short8v*)&smem[cur][0][(wr8 + 0) * 512 + lane8]; \
            short8v a0l = *(const short8v*)&smem[cur][1][(wr8 + 0) * 512 + lane8]; \
            short8v a1h = *(const short8v*)&smem[cur][0][(wr8 + 1) * 512 + lane8]; \
            short8v a1l = *(const short8v*)&smem[cur][1][(wr8 + 1) * 512 + lane8]; \
            __builtin_amdgcn_s_setprio(1);                                    \
            _Pragma("unroll")                                                 \
            for (int nf = 0; nf < 4; ++nf) {                                  \
                acc[0][nf] = MFMA16(a0h, bh[nf], acc[0][nf]);                 \
                acc[0][nf] = MFMA16(a0h, bl[nf], acc[0][nf]);                 \
                acc[0][nf] = MFMA16(a0l, bh[nf], acc[0][nf]);                 \
                acc[1][nf] = MFMA16(a1h, bh[nf], acc[1][nf]);                 \
                acc[1][nf] = MFMA16(a1h, bl[nf], acc[1][nf]);                 \
                acc[1][nf] = MFMA16(a1l, bh[nf], acc[1][nf]);                 \
            }                                                                 \
            __builtin_amdgcn_s_setprio(0);                                    \
        }                                                                     \
        BARRIER();                                                            \
        /* phases 1..3 */                                                     \
        _Pragma("unroll")                                                     \
        for (int j = 1; j < 4; ++j) {                                         \
            short8v a0h = *(const short8v*)&smem[cur][0][(wr8 + 2*j) * 512 + lane8];     \
            short8v a0l = *(const short8v*)&smem[cur][1][(wr8 + 2*j) * 512 + lane8];     \
            short8v a1h = *(const short8v*)&smem[cur][0][(wr8 + 2*j + 1) * 512 + lane8]; \
            short8v a1l = *(const short8v*)&smem[cur][1][(wr8 + 2*j + 1) * 512 + lane8]; \
            BARRIER();                                                        \
            __builtin_amdgcn_s_setprio(1);                                    \
            _Pragma("unroll")                                                 \
            for (int nf = 0; nf < 4; ++nf) {                                  \
                acc[2*j][nf]   = MFMA16(a0h, bh[nf], acc[2*j][nf]);           \
                acc[2*j][nf]   = MFMA16(a0h, bl[nf], acc[2*j][nf]);           \
                acc[2*j][nf]   = MFMA16(a0l, bh[nf], acc[2*j][nf]);           \
                acc[2*j+1][nf] = MFMA16(a1h, bh[nf], acc[2*j+1][nf]);         \
                acc[2*j+1][nf] = MFMA16(a1h, bl[nf], acc[2*j+1][nf]);         \
                acc[2*j+1][nf] = MFMA16(a1l, bh[nf], acc[2*j+1][nf]);         \
            }                                                                 \
            __builtin_amdgcn_s_setprio(0);                                    \
            if (j < 3) BARRIER();                                             \
        }                                                                     \
        ASM_LGKM0();                                                          \
        BARRIER();                                                            \
    }

// GEMM1: proj(hi,lo)[V][D] = codebook(hi,lo)[V][CD] @ w(hi,lo)[D][CD]^T + b
__global__ __launch_bounds__(512, 2) void vq_gemm1_8p(
    const unsigned short* __restrict__ Ahp, const unsigned short* __restrict__ Alp,
    const unsigned short* __restrict__ Bhp, const unsigned short* __restrict__ Blp,
    const float* __restrict__ bias,
    unsigned short* __restrict__ Phi, unsigned short* __restrict__ Plo)
{
    __shared__ unsigned short smem[2][4][8192];   // 128 KiB
    const int wg = xcd_swz(blockIdx.x, (V_/256) * (D_/256));
    const int mt = (wg >> 2) * 256;   // V
    const int nt = (wg & 3) * 256;    // D

    GEMM_CORE_8P(CD_)

    // epilogue: +bias, split to hi/lo planes.  C/D: col=lane&15, row=kg*4+r
    #pragma unroll
    for (int nf = 0; nf < 4; ++nf) {
        const int col = nt + wc * 64 + nf * 16 + r16;
        const float bv = bias[col];
        #pragma unroll
        for (int mf = 0; mf < 8; ++mf) {
            const int rbase = mt + wr * 128 + mf * 16 + kg * 4;
            #pragma unroll
            for (int r = 0; r < 4; ++r) {
                float vv = acc[mf][nf][r] + bv;
                unsigned short h = f2bf(vv);
                unsigned short l = f2bf(vv - bf2f(h));
                size_t o = (size_t)(rbase + r) * D_ + col;
                Phi[o] = h; Plo[o] = l;
            }
        }
    }
}

// GEMM2: scores enc x proj^T (split-bf16, 3-pass), fused scaled argmax
__global__ __launch_bounds__(512, 2) void vq_gemm2_8p(
    const unsigned short* __restrict__ Ahp, const unsigned short* __restrict__ Alp,
    const unsigned short* __restrict__ Bhp, const unsigned short* __restrict__ Blp,
    const float* __restrict__ ninv,
    float* __restrict__ pmax, int* __restrict__ pidx)
{
    __shared__ unsigned short smem[2][4][8192];   // 128 KiB
    const int wg = xcd_swz(blockIdx.x, (NR/256) * VT2);
    const int nid = wg >> 3;          // 0..124 V-tile
    const int mt = (wg & 7) * 256;    // rows
    const int nt = nid * 256;         // V

    GEMM_CORE_8P(D_)

    // scaled argmax; ties -> smallest v everywhere (ascending scan, strict >)
    float* redv = (float*)&smem[0][0][0];      // [256][4] f32
    int*   redi = (int*)&smem[0][0][2048];     // [256][4] i32
    float nv[4];
    #pragma unroll
    for (int nf = 0; nf < 4; ++nf) nv[nf] = ninv[nt + wc * 64 + nf * 16 + r16];
    #pragma unroll
    for (int mf = 0; mf < 8; ++mf) {
        #pragma unroll
        for (int r = 0; r < 4; ++r) {
            float best = -INFINITY; int bi = 0x7fffffff;
            #pragma unroll
            for (int nf = 0; nf < 4; ++nf) {
                float v = acc[mf][nf][r] * nv[nf];
                int ci = nt + wc * 64 + nf * 16 + r16;
                if (v > best || (v == best && ci < bi)) { best = v; bi = ci; }
            }
            #pragma unroll
            for (int m = 8; m >= 1; m >>= 1) {
                float ov = __shfl_xor(best, m, 16);
                int   oi = __shfl_xor(bi,   m, 16);
                if (ov > best || (ov == best && oi < bi)) { best = ov; bi = oi; }
            }
            if (r16 == 0) {
                int rl = wr * 128 + mf * 16 + kg * 4 + r;
                redv[rl * 4 + wc] = best; redi[rl * 4 + wc] = bi;
            }
        }
    }
    BARRIER();
    if (threadIdx.x < 256) {
        float best = -INFINITY; int bi = 0x7fffffff;
        #pragma unroll
        for (int c = 0; c < 4; ++c) {
            float v = redv[threadIdx.x * 4 + c];
            int   i = redi[threadIdx.x * 4 + c];
            if (v > best || (v == best && i < bi)) { best = v; bi = i; }
        }
        size_t o = (size_t)(mt + threadIdx.x) * VT2 + nid;
        pmax[o] = best; pidx[o] = bi;
    }
}

// ---------------------------------------------------------------------------
// HYBRID gemm1 (round-3 verified: reg-staged f32 A + in-kernel cvt), used
// only when ws_size can't hold the codebook planes.
// ---------------------------------------------------------------------------
__global__ __launch_bounds__(256) void vq_gemm1_mfma(
    const float* __restrict__ A,
    const unsigned short* __restrict__ Bhi, const unsigned short* __restrict__ Blo,
    const float* __restrict__ bias,
    unsigned short* __restrict__ Phi, unsigned short* __restrict__ Plo)
{
    __shared__ unsigned short smem[2][4][4096];
    const int tid = threadIdx.x;
    const int lane = tid & 63, w = tid >> 6;
    const int wr = w >> 1, wc = w & 1;
    const int m_tile = blockIdx.y * 128;   // V
    const int n_tile = blockIdx.x * 128;   // D
    const int row16 = lane & 15, kg = lane >> 4;
    const int s0 = 2 * w, s1 = s0 + 1;
    const int lane8 = lane * 8, wr4 = wr * 4, wc4 = wc * 4;

    const float*          Ap0 = A   + (size_t)(m_tile + s0*16 + row16) * CD_ + kg*8;
    const float*          Ap1 = A   + (size_t)(m_tile + s1*16 + row16) * CD_ + kg*8;
    const unsigned short* Bp0 = Bhi + (size_t)(n_tile + s0*16 + row16) * CD_ + kg*8;
    const unsigned short* Bp1 = Bhi + (size_t)(n_tile + s1*16 + row16) * CD_ + kg*8;
    const unsigned short* Lp0 = Blo + (size_t)(n_tile + s0*16 + row16) * CD_ + kg*8;
    const unsigned short* Lp1 = Blo + (size_t)(n_tile + s1*16 + row16) * CD_ + kg*8;

    f32x4 acc[4][4];
    #pragma unroll
    for (int i = 0; i < 4; ++i)
        #pragma unroll
        for (int j = 0; j < 4; ++j) acc[i][j] = (f32x4){0.f, 0.f, 0.f, 0.f};

    float4 aw[4], al_[4];
    aw[0] = *(const float4*)(Ap0);     aw[1] = *(const float4*)(Ap0 + 4);
    aw[2] = *(const float4*)(Ap1);     aw[3] = *(const float4*)(Ap1 + 4);
    glds16(Bp0, (unsigned short*)&smem[0][2][s0*512]);
    glds16(Bp1, (unsigned short*)&smem[0][2][s1*512]);
    glds16(Lp0, (unsigned short*)&smem[0][3][s0*512]);
    glds16(Lp1, (unsigned short*)&smem[0][3][s1*512]);
    {
        short8v h0, l0, h1, l1;
        cvt8(aw[0], aw[1], h0, l0);
        cvt8(aw[2], aw[3], h1, l1);
        *(short8v*)&smem[0][0][s0*512 + lane8] = h0;
        *(short8v*)&smem[0][1][s0*512 + lane8] = l0;
        *(short8v*)&smem[0][0][s1*512 + lane8] = h1;
        *(short8v*)&smem[0][1][s1*512 + lane8] = l1;
    }
    aw[0] = *(const float4*)(Ap0 + 32); aw[1] = *(const float4*)(Ap0 + 36);
    aw[2] = *(const float4*)(Ap1 + 32); aw[3] = *(const float4*)(Ap1 + 36);
    __syncthreads();

    int cur = 0;
    const int NT = CD_ / 32;
    for (int t = 0; t < NT; ++t) {
        if (t + 1 < NT) {
            const size_t ko = (size_t)(t + 1) * 32;
            glds16(Bp0 + ko, (unsigned short*)&smem[cur^1][2][s0*512]);
            glds16(Bp1 + ko, (unsigned short*)&smem[cur^1][2][s1*512]);
            glds16(Lp0 + ko, (unsigned short*)&smem[cur^1][3][s0*512]);
            glds16(Lp1 + ko, (unsigned short*)&smem[cur^1][3][s1*512]);
            short8v h0, l0, h1, l1;
            cvt8(aw[0], aw[1], h0, l0);
            cvt8(aw[2], aw[3], h1, l1);
            *(short8v*)&smem[cur^1][0][s0*512 + lane8] = h0;
            *(short8v*)&smem[cur^1][1][s0*512 + lane8] = l0;
            *(short8v*)&smem[cur^1][0][s1*512 + lane8] = h1;
            *(short8v*)&smem[cur^1][1][s1*512 + lane8] = l1;
        }
        if (t + 2 < NT) {
            const size_t ko2 = (size_t)(t + 2) * 32;
            al_[0] = *(const float4*)(Ap0 + ko2);  al_[1] = *(const float4*)(Ap0 + ko2 + 4);
            al_[2] = *(const float4*)(Ap1 + ko2);  al_[3] = *(const float4*)(Ap1 + ko2 + 4);
        }
        short8v ah[4], av[4], bh[4], bl[4];
        #pragma unroll
        for (int f = 0; f < 4; ++f) {
            ah[f] = *(const short8v*)&smem[cur][0][(wr4+f)*512 + lane8];
            av[f] = *(const short8v*)&smem[cur][1][(wr4+f)*512 + lane8];
            bh[f] = *(const short8v*)&smem[cur][2][(wc4+f)*512 + lane8];
            bl[f] = *(const short8v*)&smem[cur][3][(wc4+f)*512 + lane8];
        }
        #pragma unroll
        for (int mf = 0; mf < 4; ++mf)
            #pragma unroll
            for (int nf = 0; nf < 4; ++nf) {
                acc[mf][nf] = MFMA16(ah[mf], bh[nf], acc[mf][nf]);
                acc[mf][nf] = MFMA16(ah[mf], bl[nf], acc[mf][nf]);
                acc[mf][nf] = MFMA16(av[mf], bh[nf], acc[mf][nf]);
            }
        __syncthreads();
        #pragma unroll
        for (int q = 0; q < 4; ++q) aw[q] = al_[q];
        cur ^= 1;
    }

    #pragma unroll
    for (int nf = 0; nf < 4; ++nf) {
        const int col = n_tile + wc*64 + nf*16 + row16;
        const float bv = bias[col];
        #pragma unroll
        for (int mf = 0; mf < 4; ++mf) {
            const int rbase = m_tile + wr*64 + mf*16 + kg*4;
            #pragma unroll
            for (int r = 0; r < 4; ++r) {
                float vv = acc[mf][nf][r] + bv;
                unsigned short h = f2bf(vv);
                unsigned short l = f2bf(vv - bf2f(h));
                size_t o = (size_t)(rbase + r) * D_ + col;
                Phi[o] = h; Plo[o] = l;
            }
        }
    }
}

// ---------------------------------------------------------------------------
// row-norm reciprocal from hi/lo planes
// ---------------------------------------------------------------------------
__global__ __launch_bounds__(256) void vq_norms_pl(const unsigned short* __restrict__ ph,
                                                   const unsigned short* __restrict__ pl,
                                                   float* __restrict__ ninv) {
    const int row  = blockIdx.x * 4 + (threadIdx.x >> 6);
    const int lane = threadIdx.x & 63;
    float s = 0.f;
    #pragma unroll
    for (int q = 0; q < 2; ++q) {
        size_t o = (size_t)row * D_ + q * 512 + lane * 8;
        short8v h = *(const short8v*)(ph + o);
        short8v l = *(const short8v*)(pl + o);
        #pragma unroll
        for (int e = 0; e < 8; ++e) {
            float x = bf2f((unsigned short)h[e]) + bf2f((unsigned short)l[e]);
            s += x * x;
        }
    }
    #pragma unroll
    for (int off = 32; off >= 1; off >>= 1) s += __shfl_down(s, off);
    if (lane == 0) ninv[row] = 1.0f / fmaxf(sqrtf(s), 1e-12f);
}

// ---------------------------------------------------------------------------
// z[b][d][t] -> enc hi/lo planes [b*T+t][d]
// ---------------------------------------------------------------------------
__global__ __launch_bounds__(256) void vq_transpose_cvt(const float* __restrict__ z,
                                                        unsigned short* __restrict__ ehi,
                                                        unsigned short* __restrict__ elo) {
    __shared__ float tile[64][65];
    const int b = blockIdx.z, t0 = blockIdx.x * 64, d0 = blockIdx.y * 64;
    const int lane = threadIdx.x & 63, sub = threadIdx.x >> 6;
    for (int dd = sub; dd < 64; dd += 4)
        tile[dd][lane] = z[((size_t)b * D_ + d0 + dd) * T_ + t0 + lane];
    __syncthreads();
    for (int tt = sub; tt < 64; tt += 4) {
        float v = tile[lane][tt];
        unsigned short h = f2bf(v);
        unsigned short l = f2bf(v - bf2f(h));
        size_t o = (size_t)(b * T_ + t0 + tt) * D_ + d0 + lane;
        ehi[o] = h; elo[o] = l;
    }
}

// ---------------------------------------------------------------------------
// merge per-tile argmax partials (v-ascending) -> final index
// ---------------------------------------------------------------------------
__global__ __launch_bounds__(256) void vq_argmerge(const float* __restrict__ pmax,
                                                   const int* __restrict__ pidx,
                                                   int* __restrict__ idxw,
                                                   float* __restrict__ outI,
                                                   int vt) {
    const int i = blockIdx.x * 256 + threadIdx.x;
    if (i >= NR) return;
    float best = -INFINITY; int bi = 0;
    for (int c = 0; c < vt; c++) {
        float v = pmax[(size_t)i * vt + c];
        int   ii = pidx[(size_t)i * vt + c];
        if (v > best || (v == best && ii < bi)) { best = v; bi = ii; }
    }
    idxw[i] = bi;
    outI[i] = (float)bi;
}

// ---------------------------------------------------------------------------
// gather from hi/lo planes + loss partials
// ---------------------------------------------------------------------------
__global__ __launch_bounds__(256) void vq_gather_pl(const unsigned short* __restrict__ ph,
                                                    const unsigned short* __restrict__ pl,
                                                    const int* __restrict__ idxw,
                                                    const float* __restrict__ z,
                                                    float* __restrict__ out0,
                                                    float* __restrict__ lpart) {
    __shared__ float zq[64][65];
    __shared__ int idx_s[64];
    __shared__ float wsum[4];
    const int b = blockIdx.z, t0 = blockIdx.x * 64, d0 = blockIdx.y * 64;
    const int tid = threadIdx.x;
    const int lane = tid & 63, sub = tid >> 6;
    if (tid < 64) idx_s[tid] = idxw[b * T_ + t0 + tid];
    __syncthreads();
    for (int tt = sub; tt < 64; tt += 4) {
        size_t o = (size_t)idx_s[tt] * D_ + d0 + lane;
        zq[tt][lane] = bf2f(ph[o]) + bf2f(pl[o]);
    }
    __syncthreads();
    float lacc = 0.f;
    for (int dd = sub; dd < 64; dd += 4) {
        const size_t base = ((size_t)b * D_ + d0 + dd) * T_ + t0 + lane;
        float q = zq[lane][dd];
        float zv = z[base];
        out0[base] = q;
        float dv = zv - q;
        lacc += dv * dv;
    }
    #pragma unroll
    for (int off = 32; off >= 1; off >>= 1) lacc += __shfl_down(lacc, off);
    if (lane == 0) wsum[sub] = lacc;
    __syncthreads();
    if (tid == 0)
        lpart[(blockIdx.z * 16 + blockIdx.y) * 8 + blockIdx.x] =
            wsum[0] + wsum[1] + wsum[2] + wsum[3];
}

__global__ void vq_loss(const float* __restrict__ lpart, float* __restrict__ outL) {
    const int b = threadIdx.x;
    if (b >= B_) return;
    float s = 0.f;
    for (int q = 0; q < 128; q++) s += lpart[b * 128 + q];
    s /= (float)(D_ * T_);
    outL[b]      = s;
    outL[B_ + b] = s;
}

// ===========================================================================
extern "C" void kernel_launch(void* const* d_in, const int* in_sizes, int n_in,
                              void* d_out, int out_size, void* d_ws, size_t ws_size,
                              hipStream_t stream) {
    const float* z        = (const float*)d_in[0];   // [B, D, T]
    const float* codebook = (const float*)d_in[1];   // [V, CD]
    const float* cb_w     = (const float*)d_in[2];   // [D, CD]
    const float* cb_b     = (const float*)d_in[3];   // [D]

    float* out0 = (float*)d_out;
    float* outI = out0 + (size_t)B_*D_*T_;
    float* outL = outI + NR;

    char* p = (char*)d_ws;
    auto alloc = [&](size_t bytes) { char* r = p; p += (bytes + 255) & ~(size_t)255; return r; };
    // hybrid prefix (fits: round-3 ran with this footprint)
    unsigned short* w_hi = (unsigned short*)alloc((size_t)D_ * CD_ * 2);
    unsigned short* w_lo = (unsigned short*)alloc((size_t)D_ * CD_ * 2);
    unsigned short* p_hi = (unsigned short*)alloc((size_t)V_ * D_ * 2);
    unsigned short* p_lo = (unsigned short*)alloc((size_t)V_ * D_ * 2);
    unsigned short* e_hi = (unsigned short*)alloc((size_t)NR * D_ * 2);
    unsigned short* e_lo = (unsigned short*)alloc((size_t)NR * D_ * 2);
    float* ninv  = (float*)alloc((size_t)V_ * 4);
    float* pmax  = (float*)alloc((size_t)NR * VT2 * 4);
    int*   pidx  = (int*)  alloc((size_t)NR * VT2 * 4);
    int*   idxw  = (int*)  alloc((size_t)NR * 4);
    float* lpart = (float*)alloc((size_t)2048 * 4);
    // full-path extension: codebook planes (524 MB)
    unsigned short* c_hi = (unsigned short*)alloc((size_t)V_ * CD_ * 2);
    unsigned short* c_lo = (unsigned short*)alloc((size_t)V_ * CD_ * 2);
    size_t need_full = (size_t)(p - (char*)d_ws);

    // common prep
    vq_cvt<<<1024, 256, 0, stream>>>(cb_w, w_hi, w_lo, (size_t)D_ * CD_ / 4);
    vq_transpose_cvt<<<dim3(T_/64, D_/64, B_), 256, 0, stream>>>(z, e_hi, e_lo);

    if (ws_size >= need_full) {
        vq_cvt<<<4096, 256, 0, stream>>>(codebook, c_hi, c_lo, (size_t)V_ * CD_ / 4);
        vq_gemm1_8p<<<(V_/256) * (D_/256), 512, 0, stream>>>(c_hi, c_lo, w_hi, w_lo,
                                                             cb_b, p_hi, p_lo);
    } else {
        vq_gemm1_mfma<<<dim3(D_/128, V_/128), 256, 0, stream>>>(codebook, w_hi, w_lo,
                                                                cb_b, p_hi, p_lo);
    }
    vq_norms_pl<<<V_/4, 256, 0, stream>>>(p_hi, p_lo, ninv);
    vq_gemm2_8p<<<(NR/256) * VT2, 512, 0, stream>>>(e_hi, e_lo, p_hi, p_lo,
                                                    ninv, pmax, pidx);
    vq_argmerge<<<NR/256, 256, 0, stream>>>(pmax, pidx, idxw, outI, VT2);
    vq_gather_pl<<<dim3(T_/64, D_/64, B_), 256, 0, stream>>>(p_hi, p_lo, idxw, z,
                                                             out0, lpart);
    vq_loss<<<1, 64, 0, stream>>>(lpart, outL);
}